// Round 11
// baseline (266.507 us; speedup 1.0000x reference)
//
#include <hip/hip_runtime.h>

#define SS 1024
#define BB 4096
#define HH 8
#define XSTRIDE (BB * HH)   // floats per timestep slice
#define NG 256              // groups of 4 steps

typedef float f32x2 __attribute__((ext_vector_type(2)));

// DPP cross-lane (VALU pipe): xor1/xor2 via quad_perm, xor7 via row_half_mirror.
__device__ __forceinline__ int dpp_x1(int v) { return __builtin_amdgcn_mov_dpp(v, 0xB1, 0xF, 0xF, true); }
__device__ __forceinline__ int dpp_x2(int v) { return __builtin_amdgcn_mov_dpp(v, 0x4E, 0xF, 0xF, true); }
__device__ __forceinline__ int dpp_x7(int v) { return __builtin_amdgcn_mov_dpp(v, 0x141, 0xF, 0xF, true); }

// Butterfly register m holds v[j ^ MK[m]]; both weight sets pre-permuted to match.
__device__ __constant__ int MK_[8] = {0, 1, 2, 3, 7, 6, 5, 4};

// Pinned distributed loads: 4B/lane. Q-chain data sits exactly 256B after P's
// (batches base+8..base+15), so the SAME address register serves both chains.
#define ALOADP(DST, PTR) asm volatile("global_load_dword %0, %1, off" : "=v"(DST) : "v"(PTR))
#define ALOADQ(DST, PTR) asm volatile("global_load_dword %0, %1, off offset:256" : "=v"(DST) : "v"(PTR))

#define WAITV(N) do {                                                                  \
    asm volatile("s_waitcnt vmcnt(" #N ")" ::: "memory");                              \
    __builtin_amdgcn_sched_barrier(0);                                                 \
} while (0)

// Butterfly one scalar across the 8-lane group into 4 MK-ordered f32x2 pairs.
#define BFLY8(SRC, DV) do {                                                            \
    const int b0_ = __float_as_int(SRC);                                               \
    const int b1_ = dpp_x1(b0_);                                                       \
    const int b2_ = dpp_x2(b0_);                                                       \
    const int b3_ = dpp_x2(b1_);                                                       \
    const int b4_ = dpp_x7(b0_);                                                       \
    const int b5_ = dpp_x7(b1_);                                                       \
    const int b6_ = dpp_x7(b2_);                                                       \
    const int b7_ = dpp_x7(b3_);                                                       \
    DV[0] = (f32x2){(SRC), __int_as_float(b1_)};                                       \
    DV[1] = (f32x2){__int_as_float(b2_), __int_as_float(b3_)};                         \
    DV[2] = (f32x2){__int_as_float(b4_), __int_as_float(b5_)};                         \
    DV[3] = (f32x2){__int_as_float(b6_), __int_as_float(b7_)};                         \
} while (0)

// hv refresh of one chain from its new h (same butterfly).
#define BFLYH(C) do {                                                                  \
    const int hb_ = __float_as_int(C##h);                                              \
    const int t1_ = dpp_x1(hb_);                                                       \
    const int t2_ = dpp_x2(hb_);                                                       \
    const int t3_ = dpp_x2(t1_);                                                       \
    const int t4_ = dpp_x7(hb_);                                                       \
    const int t5_ = dpp_x7(t1_);                                                       \
    const int t6_ = dpp_x7(t2_);                                                       \
    const int t7_ = dpp_x7(t3_);                                                       \
    C##hv[0] = (f32x2){C##h, __int_as_float(t1_)};                                     \
    C##hv[1] = (f32x2){__int_as_float(t2_), __int_as_float(t3_)};                      \
    C##hv[2] = (f32x2){__int_as_float(t4_), __int_as_float(t5_)};                      \
    C##hv[3] = (f32x2){__int_as_float(t6_), __int_as_float(t7_)};                      \
} while (0)

// X pre-activations for step V, BOTH chains (head steps 0,1 of each group).
// Weights PRE-SCALED: r/z rows by -log2(e), n rows by +2*log2(e).
#define XFULL2(PB, QB, V) do {                                                         \
    f32x2 pxv[4], qxv[4];                                                              \
    BFLY8(PB[V], pxv);                                                                 \
    BFLY8(QB[V], qxv);                                                                 \
    f32x2 psr = {bias_r, 0.0f}, qsr = {bias_r, 0.0f};                                  \
    f32x2 psz = {bias_z, 0.0f}, qsz = {bias_z, 0.0f};                                  \
    f32x2 psn = {bni_s, 0.0f},  qsn = {bni_s, 0.0f};                                   \
    _Pragma("unroll")                                                                  \
    for (int p_ = 0; p_ < 4; ++p_) {                                                   \
        psr = __builtin_elementwise_fma(pxv[p_], wri[p_], psr);                        \
        qsr = __builtin_elementwise_fma(qxv[p_], wri[p_], qsr);                        \
        psz = __builtin_elementwise_fma(pxv[p_], wzi[p_], psz);                        \
        qsz = __builtin_elementwise_fma(qxv[p_], wzi[p_], qsz);                        \
        psn = __builtin_elementwise_fma(pxv[p_], wni[p_], psn);                        \
        qsn = __builtin_elementwise_fma(qxv[p_], wni[p_], qsn);                        \
    }                                                                                  \
    Pxr[(V)] = psr.x + psr.y; Qxr[(V)] = qsr.x + qsr.y;                                \
    Pxz[(V)] = psz.x + psz.y; Qxz[(V)] = qsz.x + qsz.y;                                \
    Pxn[(V)] = psn.x + psn.y; Qxn[(V)] = qsn.x + qsn.y;                                \
} while (0)

// One 4-step group, BOTH chains interleaved. Steps 0,1 additionally weave
// X(u+2) of both chains into the transcendental stall windows. Each chain's
// ~170cyc dependent chain is filled by the OTHER chain's independent issue.
#define GROUP(PB, QB) do {                                                             \
    XFULL2(PB, QB, 0);                                                                 \
    XFULL2(PB, QB, 1);                                                                 \
    _Pragma("unroll")                                                                  \
    for (int u = 0; u < 4; ++u) {                                                      \
        /* S1: h-dots, both chains (24 pk_fma, 6 independent chains) */                \
        f32x2 Pr2 = {Pxr[u], 0.0f}, Qr2 = {Qxr[u], 0.0f};                              \
        f32x2 Pz2 = {Pxz[u], 0.0f}, Qz2 = {Qxz[u], 0.0f};                              \
        f32x2 Pn2 = {bnh_s, 0.0f},  Qn2 = {bnh_s, 0.0f};                               \
        _Pragma("unroll")                                                              \
        for (int p_ = 0; p_ < 4; ++p_) {                                               \
            Pr2 = __builtin_elementwise_fma(Phv[p_], wrh[p_], Pr2);                    \
            Qr2 = __builtin_elementwise_fma(Qhv[p_], wrh[p_], Qr2);                    \
            Pz2 = __builtin_elementwise_fma(Phv[p_], wzh[p_], Pz2);                    \
            Qz2 = __builtin_elementwise_fma(Qhv[p_], wzh[p_], Qz2);                    \
            Pn2 = __builtin_elementwise_fma(Phv[p_], wnh[p_], Pn2);                    \
            Qn2 = __builtin_elementwise_fma(Qhv[p_], wnh[p_], Qn2);                    \
        }                                                                              \
        const float Psr = Pr2.x + Pr2.y, Qsr = Qr2.x + Qr2.y;                          \
        const float Psz = Pz2.x + Pz2.y, Qsz = Qz2.x + Qz2.y;                          \
        const float Psn = Pn2.x + Pn2.y, Qsn = Qn2.x + Qn2.y;                          \
        const bool W = (u + 2 < 4);                                                    \
        f32x2 pxv[4], qxv[4], psr_, psz_, psn_, qsr_, qsz_, qsn_;                      \
        if (W) {   /* weave X(u+2) part 1: butterflies + first 12 pk_fma */            \
            BFLY8(PB[u + 2], pxv);                                                     \
            BFLY8(QB[u + 2], qxv);                                                     \
            psr_ = (f32x2){bias_r, 0.0f}; qsr_ = (f32x2){bias_r, 0.0f};                \
            psz_ = (f32x2){bias_z, 0.0f}; qsz_ = (f32x2){bias_z, 0.0f};                \
            psn_ = (f32x2){bni_s, 0.0f};  qsn_ = (f32x2){bni_s, 0.0f};                 \
            psr_ = __builtin_elementwise_fma(pxv[0], wri[0], psr_);                    \
            qsr_ = __builtin_elementwise_fma(qxv[0], wri[0], qsr_);                    \
            psz_ = __builtin_elementwise_fma(pxv[0], wzi[0], psz_);                    \
            qsz_ = __builtin_elementwise_fma(qxv[0], wzi[0], qsz_);                    \
            psn_ = __builtin_elementwise_fma(pxv[0], wni[0], psn_);                    \
            qsn_ = __builtin_elementwise_fma(qxv[0], wni[0], qsn_);                    \
            psr_ = __builtin_elementwise_fma(pxv[1], wri[1], psr_);                    \
            qsr_ = __builtin_elementwise_fma(qxv[1], wri[1], qsr_);                    \
            psz_ = __builtin_elementwise_fma(pxv[1], wzi[1], psz_);                    \
            qsz_ = __builtin_elementwise_fma(qxv[1], wzi[1], qsz_);                    \
            psn_ = __builtin_elementwise_fma(pxv[1], wni[1], psn_);                    \
            qsn_ = __builtin_elementwise_fma(qxv[1], wni[1], qsn_);                    \
        }                                                                              \
        const float PEr = __builtin_amdgcn_exp2f(Psr);                                 \
        const float QEr = __builtin_amdgcn_exp2f(Qsr);                                 \
        const float PEz = __builtin_amdgcn_exp2f(Psz);                                 \
        const float QEz = __builtin_amdgcn_exp2f(Qsz);                                 \
        if (W) {   /* weave X(u+2) part 2: last 12 pk_fma */                           \
            psr_ = __builtin_elementwise_fma(pxv[2], wri[2], psr_);                    \
            qsr_ = __builtin_elementwise_fma(qxv[2], wri[2], qsr_);                    \
            psz_ = __builtin_elementwise_fma(pxv[2], wzi[2], psz_);                    \
            qsz_ = __builtin_elementwise_fma(qxv[2], wzi[2], qsz_);                    \
            psn_ = __builtin_elementwise_fma(pxv[2], wni[2], psn_);                    \
            qsn_ = __builtin_elementwise_fma(qxv[2], wni[2], qsn_);                    \
            psr_ = __builtin_elementwise_fma(pxv[3], wri[3], psr_);                    \
            qsr_ = __builtin_elementwise_fma(qxv[3], wri[3], qsr_);                    \
            psz_ = __builtin_elementwise_fma(pxv[3], wzi[3], psz_);                    \
            qsz_ = __builtin_elementwise_fma(qxv[3], wzi[3], qsz_);                    \
            psn_ = __builtin_elementwise_fma(pxv[3], wni[3], psn_);                    \
            qsn_ = __builtin_elementwise_fma(qxv[3], wni[3], qsn_);                    \
        }                                                                              \
        const float Pr_ = __builtin_amdgcn_rcpf(1.0f + PEr);                           \
        const float Qr_ = __builtin_amdgcn_rcpf(1.0f + QEr);                           \
        const float Pz_ = __builtin_amdgcn_rcpf(1.0f + PEz);                           \
        const float Qz_ = __builtin_amdgcn_rcpf(1.0f + QEz);                           \
        if (W) {   /* weave X(u+2) reduce */                                           \
            Pxr[u + 2] = psr_.x + psr_.y; Qxr[u + 2] = qsr_.x + qsr_.y;                \
            Pxz[u + 2] = psz_.x + psz_.y; Qxz[u + 2] = qsz_.x + qsz_.y;                \
            Pxn[u + 2] = psn_.x + psn_.y; Qxn[u + 2] = qsn_.x + qsn_.y;                \
        }                                                                              \
        const float PEn = __builtin_amdgcn_exp2f(fmaf(Pr_, Psn, Pxn[u]));              \
        const float QEn = __builtin_amdgcn_exp2f(fmaf(Qr_, Qsn, Qxn[u]));              \
        const float Pn_ = fmaf(-2.0f, __builtin_amdgcn_rcpf(1.0f + PEn), 1.0f);        \
        const float Qn_ = fmaf(-2.0f, __builtin_amdgcn_rcpf(1.0f + QEn), 1.0f);        \
        Ph = Pn_ + Pz_ * (Ph - Pn_);                                                   \
        Qh = Qn_ + Qz_ * (Qh - Qn_);                                                   \
        BFLYH(P);                                                                      \
        BFLYH(Q);                                                                      \
        __builtin_nontemporal_store(Ph, Pop + (size_t)u * XSTRIDE);                    \
        __builtin_nontemporal_store(Qh, Pop + (size_t)u * XSTRIDE + 64);               \
    }                                                                                  \
    Pop += 4 * (size_t)XSTRIDE;                                                        \
} while (0)

// 8 pinned dword loads per group (4 addresses x {P: offset 0, Q: offset 256});
// the 4 address registers self-advance by one group (512 KiB).
#define LOADG(PB, QB) do {                                                             \
    ALOADP(PB[0], pa0); ALOADQ(QB[0], pa0);                                            \
    ALOADP(PB[1], pa1); ALOADQ(QB[1], pa1);                                            \
    ALOADP(PB[2], pa2); ALOADQ(QB[2], pa2);                                            \
    ALOADP(PB[3], pa3); ALOADQ(QB[3], pa3);                                            \
    pa0 += 4 * (size_t)XSTRIDE; pa1 += 4 * (size_t)XSTRIDE;                            \
    pa2 += 4 * (size_t)XSTRIDE; pa3 += 4 * (size_t)XSTRIDE;                            \
} while (0)

// 8 lanes per batch element; TWO chains (P,Q) of 8 batches per wave ->
// 16 batches/wave, 256 waves. Dual-chain static ILP: the in-order wave always
// has the other chain's independent ops to issue during a chain's ~170cyc
// dependent path (h-dots -> exp2 -> rcp -> exp2 -> rcp -> update).
__global__ __launch_bounds__(64, 1) void gru_kernel(
    const float* __restrict__ x,
    const float* __restrict__ w_ih,
    const float* __restrict__ w_hh,
    const float* __restrict__ b_ih,
    const float* __restrict__ b_hh,
    float* __restrict__ out)
{
    const int lane = threadIdx.x;
    const int j = lane & 7;

    const float SR = -1.4426950408889634f;     // -log2(e): sigmoid scale
    const float SN = 2.8853900817779268f;      // 2*log2(e): tanh scale

    // Both weight sets MK-permuted (columns j ^ MK[m]) to match butterfly order.
    f32x2 wri[4], wzi[4], wni[4], wrh[4], wzh[4], wnh[4];
    #pragma unroll
    for (int p = 0; p < 4; ++p) {
        const int c0 = j ^ MK_[2 * p], c1 = j ^ MK_[2 * p + 1];
        wri[p] = (f32x2){SR * w_ih[j * 8 + c0],        SR * w_ih[j * 8 + c1]};
        wzi[p] = (f32x2){SR * w_ih[(8 + j) * 8 + c0],  SR * w_ih[(8 + j) * 8 + c1]};
        wni[p] = (f32x2){SN * w_ih[(16 + j) * 8 + c0], SN * w_ih[(16 + j) * 8 + c1]};
        wrh[p] = (f32x2){SR * w_hh[j * 8 + c0],        SR * w_hh[j * 8 + c1]};
        wzh[p] = (f32x2){SR * w_hh[(8 + j) * 8 + c0],  SR * w_hh[(8 + j) * 8 + c1]};
        wnh[p] = (f32x2){SN * w_hh[(16 + j) * 8 + c0], SN * w_hh[(16 + j) * 8 + c1]};
    }
    const float bias_r = SR * (b_ih[j] + b_hh[j]);
    const float bias_z = SR * (b_ih[8 + j] + b_hh[8 + j]);
    const float bni_s  = SN * b_ih[16 + j];
    const float bnh_s  = SN * b_hh[16 + j];

    // lane L: P covers flat element blockIdx*128 + L of each (B,H) slice;
    // Q covers +64 floats (+256B -> load/store immediate offset).
    const float* xq = x + (blockIdx.x << 7) + lane;
    float* Pop = out + (blockIdx.x << 7) + lane;

    const float* pa0 = xq;
    const float* pa1 = xq + (size_t)XSTRIDE;
    const float* pa2 = xq + 2 * (size_t)XSTRIDE;
    const float* pa3 = xq + 3 * (size_t)XSTRIDE;

    float PxA[4], PxB[4], QxA[4], QxB[4];   // distributed x: 16 VGPRs total

    // prologue: group 0 -> A, group 1 -> B; retire A's 8 (B's 8 in flight)
    LOADG(PxA, QxA);
    LOADG(PxB, QxB);
    WAITV(8);

    float Ph = 0.0f, Qh = 0.0f;
    f32x2 Phv[4] = {{0,0},{0,0},{0,0},{0,0}};
    f32x2 Qhv[4] = {{0,0},{0,0},{0,0},{0,0}};
    float Pxr[4], Pxz[4], Pxn[4], Qxr[4], Qxz[4], Qxn[4];

    // Steady state at each WAITV(16): newest 16 = this group's 8 stores +
    // just-issued 8 loads; the other buffer's loads (older) are retired.
    for (int g = 0; g < NG - 4; g += 2) {
        GROUP(PxA, QxA);
        LOADG(PxA, QxA);
        WAITV(16);
        GROUP(PxB, QxB);
        LOADG(PxB, QxB);
        WAITV(16);
    }
    GROUP(PxA, QxA); LOADG(PxA, QxA); WAITV(16);   // group 252; loads 254
    GROUP(PxB, QxB); LOADG(PxB, QxB); WAITV(16);   // group 253; loads 255
    GROUP(PxA, QxA); WAITV(8);                     // group 254
    GROUP(PxB, QxB);                               // group 255

    float* Phl = out + (size_t)SS * BB * HH + (blockIdx.x << 7) + lane;
    *Phl = Ph;
    *(Phl + 64) = Qh;
}

extern "C" void kernel_launch(void* const* d_in, const int* in_sizes, int n_in,
                              void* d_out, int out_size, void* d_ws, size_t ws_size,
                              hipStream_t stream) {
    const float* x    = (const float*)d_in[0];
    const float* w_ih = (const float*)d_in[1];
    const float* w_hh = (const float*)d_in[2];
    const float* b_ih = (const float*)d_in[3];
    const float* b_hh = (const float*)d_in[4];
    float* out = (float*)d_out;
    gru_kernel<<<BB / 16, 64, 0, stream>>>(x, w_ih, w_hh, b_ih, b_hh, out);
}

// Round 12
// 156.267 us; speedup vs baseline: 1.7055x; 1.7055x over previous
//
#include <hip/hip_runtime.h>

#define SS 1024
#define BB 4096
#define HH 8
#define XSTRIDE (BB * HH)   // floats per timestep slice

// DPP cross-lane (VALU pipe): xor1/xor2 via quad_perm, xor7 via row_half_mirror.
__device__ __forceinline__ int dpp_x1(int v) { return __builtin_amdgcn_mov_dpp(v, 0xB1, 0xF, 0xF, true); }
__device__ __forceinline__ int dpp_x2(int v) { return __builtin_amdgcn_mov_dpp(v, 0x4E, 0xF, 0xF, true); }
__device__ __forceinline__ int dpp_x7(int v) { return __builtin_amdgcn_mov_dpp(v, 0x141, 0xF, 0xF, true); }

// Butterfly slot m holds v[j ^ MK[m]]; both weight sets pre-permuted to match.
__device__ __constant__ int MK_[8] = {0, 1, 2, 3, 7, 6, 5, 4};

// Pinned distributed load: 4B/lane, wave = 256B coalesced, 1 distinct value
// per lane. Inline asm so the scheduler/RA cannot sink it (r2-r6 lesson).
#define ALOADD(DST, PTR) asm volatile("global_load_dword %0, %1, off" : "=v"(DST) : "v"(PTR))

#define WAITV(N) do {                                                                  \
    asm volatile("s_waitcnt vmcnt(" #N ")" ::: "memory");                              \
    __builtin_amdgcn_sched_barrier(0);                                                 \
} while (0)

// Scalar butterfly: 7 DPP results used DIRECTLY as FMA operands (r11 lesson:
// f32x2 packing cost ~16 movs/step for zero pk_fma throughput gain on fp32).
#define BFLY8S(SRC, V0, V1, V2, V3, V4, V5, V6, V7) \
    const int b0_ = __float_as_int(SRC);            \
    const int b1_ = dpp_x1(b0_);                    \
    const int b2_ = dpp_x2(b0_);                    \
    const int b3_ = dpp_x2(b1_);                    \
    const int b4_ = dpp_x7(b0_);                    \
    const int b5_ = dpp_x7(b1_);                    \
    const int b6_ = dpp_x7(b2_);                    \
    const int b7_ = dpp_x7(b3_);                    \
    const float V0 = (SRC);                         \
    const float V1 = __int_as_float(b1_);           \
    const float V2 = __int_as_float(b2_);           \
    const float V3 = __int_as_float(b3_);           \
    const float V4 = __int_as_float(b4_);           \
    const float V5 = __int_as_float(b5_);           \
    const float V6 = __int_as_float(b6_);           \
    const float V7 = __int_as_float(b7_)

// One gate's 8-dot as two 4-deep scalar chains (path ~30 cyc) + 1 add at use.
#define DOT4A(ACC0, V0, V1, V2, V3, W, O)          \
    float ACC0 = fmaf(V0, W[O + 0], ACC0##i);      \
    ACC0 = fmaf(V1, W[O + 1], ACC0);               \
    ACC0 = fmaf(V2, W[O + 2], ACC0);               \
    ACC0 = fmaf(V3, W[O + 3], ACC0)

// Full X pre-activation for step V (head steps 0,1 of each group).
// Weights/biases PRE-SCALED: r/z rows by -log2(e), n rows by +2*log2(e).
#define XFULL(BUF, V) do {                                                             \
    BFLY8S(BUF[V], xv0, xv1, xv2, xv3, xv4, xv5, xv6, xv7);                            \
    float sr0 = fmaf(xv0, wri[0], bias_r);                                             \
    float sz0 = fmaf(xv0, wzi[0], bias_z);                                             \
    float sn0 = fmaf(xv0, wni[0], bni_s);                                              \
    float sr1 = xv4 * wri[4], sz1 = xv4 * wzi[4], sn1 = xv4 * wni[4];                  \
    sr0 = fmaf(xv1, wri[1], sr0); sz0 = fmaf(xv1, wzi[1], sz0);                        \
    sn0 = fmaf(xv1, wni[1], sn0);                                                      \
    sr1 = fmaf(xv5, wri[5], sr1); sz1 = fmaf(xv5, wzi[5], sz1);                        \
    sn1 = fmaf(xv5, wni[5], sn1);                                                      \
    sr0 = fmaf(xv2, wri[2], sr0); sz0 = fmaf(xv2, wzi[2], sz0);                        \
    sn0 = fmaf(xv2, wni[2], sn0);                                                      \
    sr1 = fmaf(xv6, wri[6], sr1); sz1 = fmaf(xv6, wzi[6], sz1);                        \
    sn1 = fmaf(xv6, wni[6], sn1);                                                      \
    sr0 = fmaf(xv3, wri[3], sr0); sz0 = fmaf(xv3, wzi[3], sz0);                        \
    sn0 = fmaf(xv3, wni[3], sn0);                                                      \
    sr1 = fmaf(xv7, wri[7], sr1); sz1 = fmaf(xv7, wzi[7], sz1);                        \
    sn1 = fmaf(xv7, wni[7], sn1);                                                      \
    xr[(V)] = sr0 + sr1; xz[(V)] = sz0 + sz1; xn[(V)] = sn0 + sn1;                     \
} while (0)

// One 8-step group: R-steps with X(u+2) lexically woven (3 slices) into the
// transcendental stall windows (r7's proven placement), all scalar.
#define GROUP(BUF, SBASE) do {                                                         \
    XFULL(BUF, 0);                                                                     \
    XFULL(BUF, 1);                                                                     \
    _Pragma("unroll")                                                                  \
    for (int u = 0; u < 8; ++u) {                                                      \
        /* S1: h-dots, 6 interleaved 4-deep chains */                                  \
        float r0 = fmaf(hv0, wrh[0], xr[u]);                                           \
        float z0 = fmaf(hv0, wzh[0], xz[u]);                                           \
        float n0 = fmaf(hv0, wnh[0], bnh_s);                                           \
        float r1 = hv4 * wrh[4], z1 = hv4 * wzh[4], n1 = hv4 * wnh[4];                 \
        r0 = fmaf(hv1, wrh[1], r0); z0 = fmaf(hv1, wzh[1], z0);                        \
        n0 = fmaf(hv1, wnh[1], n0);                                                    \
        r1 = fmaf(hv5, wrh[5], r1); z1 = fmaf(hv5, wzh[5], z1);                        \
        n1 = fmaf(hv5, wnh[5], n1);                                                    \
        r0 = fmaf(hv2, wrh[2], r0); z0 = fmaf(hv2, wzh[2], z0);                        \
        n0 = fmaf(hv2, wnh[2], n0);                                                    \
        r1 = fmaf(hv6, wrh[6], r1); z1 = fmaf(hv6, wzh[6], z1);                        \
        n1 = fmaf(hv6, wnh[6], n1);                                                    \
        r0 = fmaf(hv3, wrh[3], r0); z0 = fmaf(hv3, wzh[3], z0);                        \
        n0 = fmaf(hv3, wnh[3], n0);                                                    \
        r1 = fmaf(hv7, wrh[7], r1); z1 = fmaf(hv7, wzh[7], z1);                        \
        n1 = fmaf(hv7, wnh[7], n1);                                                    \
        const float srr = r0 + r1;                                                     \
        const float szz = z0 + z1;                                                     \
        const float snn = n0 + n1;                                                     \
        const bool W = (u + 2 < 8);                                                    \
        float sr0, sr1, sz0, sz1, sn0, sn1, xv4w, xv5w, xv6w, xv7w;                    \
        if (W) {   /* X(u+2) slice 1: butterfly + chains' first half */                \
            BFLY8S(BUF[u + 2], xv0, xv1, xv2, xv3, xv4, xv5, xv6, xv7);                \
            xv4w = xv4; xv5w = xv5; xv6w = xv6; xv7w = xv7;                            \
            sr0 = fmaf(xv0, wri[0], bias_r);                                           \
            sz0 = fmaf(xv0, wzi[0], bias_z);                                           \
            sn0 = fmaf(xv0, wni[0], bni_s);                                            \
            sr0 = fmaf(xv1, wri[1], sr0); sz0 = fmaf(xv1, wzi[1], sz0);                \
            sn0 = fmaf(xv1, wni[1], sn0);                                              \
            sr0 = fmaf(xv2, wri[2], sr0); sz0 = fmaf(xv2, wzi[2], sz0);                \
            sn0 = fmaf(xv2, wni[2], sn0);                                              \
            sr0 = fmaf(xv3, wri[3], sr0); sz0 = fmaf(xv3, wzi[3], sz0);                \
            sn0 = fmaf(xv3, wni[3], sn0);                                              \
        }                                                                              \
        const float er = __builtin_amdgcn_exp2f(srr);                                  \
        const float ez = __builtin_amdgcn_exp2f(szz);                                  \
        if (W) {   /* X(u+2) slice 2: chains' second half */                           \
            sr1 = xv4w * wri[4]; sz1 = xv4w * wzi[4]; sn1 = xv4w * wni[4];             \
            sr1 = fmaf(xv5w, wri[5], sr1); sz1 = fmaf(xv5w, wzi[5], sz1);              \
            sn1 = fmaf(xv5w, wni[5], sn1);                                             \
            sr1 = fmaf(xv6w, wri[6], sr1); sz1 = fmaf(xv6w, wzi[6], sz1);              \
            sn1 = fmaf(xv6w, wni[6], sn1);                                             \
            sr1 = fmaf(xv7w, wri[7], sr1); sz1 = fmaf(xv7w, wzi[7], sz1);              \
            sn1 = fmaf(xv7w, wni[7], sn1);                                             \
        }                                                                              \
        const float r_ = __builtin_amdgcn_rcpf(1.0f + er);                             \
        const float z_ = __builtin_amdgcn_rcpf(1.0f + ez);                             \
        if (W) {   /* X(u+2) slice 3: reduce */                                        \
            xr[u + 2] = sr0 + sr1;                                                     \
            xz[u + 2] = sz0 + sz1;                                                     \
            xn[u + 2] = sn0 + sn1;                                                     \
        }                                                                              \
        const float en = __builtin_amdgcn_exp2f(fmaf(r_, snn, xn[u]));                 \
        const float n_ = fmaf(-2.0f, __builtin_amdgcn_rcpf(1.0f + en), 1.0f);          \
        h = n_ + z_ * (h - n_);                                                        \
        /* h butterfly: scalar results, no packing */                                  \
        const int hb_ = __float_as_int(h);                                             \
        const int t1_ = dpp_x1(hb_);                                                   \
        const int t2_ = dpp_x2(hb_);                                                   \
        const int t3_ = dpp_x2(t1_);                                                   \
        const int t4_ = dpp_x7(hb_);                                                   \
        const int t5_ = dpp_x7(t1_);                                                   \
        const int t6_ = dpp_x7(t2_);                                                   \
        const int t7_ = dpp_x7(t3_);                                                   \
        hv0 = h;                                                                       \
        hv1 = __int_as_float(t1_);                                                     \
        hv2 = __int_as_float(t2_);                                                     \
        hv3 = __int_as_float(t3_);                                                     \
        hv4 = __int_as_float(t4_);                                                     \
        hv5 = __int_as_float(t5_);                                                     \
        hv6 = __int_as_float(t6_);                                                     \
        hv7 = __int_as_float(t7_);                                                     \
        __builtin_nontemporal_store(h, &op[(size_t)((SBASE) + u) * XSTRIDE]);          \
    }                                                                                  \
} while (0)

// 8 pinned dword loads = one 8-step group (1 per step).
#define LOADG(BUF, GRP) do {                                                           \
    const float* bp_ = xq + (size_t)(GRP) * 8 * XSTRIDE;                               \
    _Pragma("unroll")                                                                  \
    for (int u_ = 0; u_ < 8; ++u_) ALOADD(BUF[u_], bp_ + (size_t)u_ * XSTRIDE);        \
} while (0)

// 8 lanes per batch element, 8 batches per wave, 512 waves (2/CU).
__global__ __launch_bounds__(64, 1) void gru_kernel(
    const float* __restrict__ x,
    const float* __restrict__ w_ih,
    const float* __restrict__ w_hh,
    const float* __restrict__ b_ih,
    const float* __restrict__ b_hh,
    float* __restrict__ out)
{
    const int lane = threadIdx.x;
    const int j = lane & 7;

    const float SR = -1.4426950408889634f;     // -log2(e): sigmoid scale
    const float SN = 2.8853900817779268f;      // 2*log2(e): tanh scale

    // Scalar weights, MK-permuted columns (j ^ MK[m]) matching butterfly order.
    float wri[8], wzi[8], wni[8], wrh[8], wzh[8], wnh[8];
    #pragma unroll
    for (int m = 0; m < 8; ++m) {
        const int c = j ^ MK_[m];
        wri[m] = SR * w_ih[j * 8 + c];
        wzi[m] = SR * w_ih[(8 + j) * 8 + c];
        wni[m] = SN * w_ih[(16 + j) * 8 + c];
        wrh[m] = SR * w_hh[j * 8 + c];
        wzh[m] = SR * w_hh[(8 + j) * 8 + c];
        wnh[m] = SN * w_hh[(16 + j) * 8 + c];
    }
    const float bias_r = SR * (b_ih[j] + b_hh[j]);
    const float bias_z = SR * (b_ih[8 + j] + b_hh[8 + j]);
    const float bni_s  = SN * b_ih[16 + j];
    const float bnh_s  = SN * b_hh[16 + j];

    // lane L covers batch (blockIdx<<3)+(L>>3), column L&7: flat index
    // (blockIdx<<6)+L into every (B,H) slice for x loads and out stores.
    const float* xq = x + (blockIdx.x << 6) + lane;
    float* op = out + (blockIdx.x << 6) + lane;
    float* hlast = out + (size_t)SS * BB * HH + (blockIdx.x << 6) + lane;

    float xA[8], xB[8];   // distributed x: 1 dword/lane/step

    // prologue: groups 0 -> A, 1 -> B; retire A's 8 (B's 8 stay in flight)
    LOADG(xA, 0);
    LOADG(xB, 1);
    WAITV(8);

    float h = 0.0f;
    float hv0 = 0, hv1 = 0, hv2 = 0, hv3 = 0, hv4 = 0, hv5 = 0, hv6 = 0, hv7 = 0;
    float xr[8], xz[8], xn[8];

    // Steady state at each WAITV(16): newest 16 = this group's 8 stores +
    // just-issued 8 loads; the other buffer's (older) loads are retired.
    for (int g = 0; g < 124; g += 2) {
        GROUP(xA, g * 8);
        LOADG(xA, g + 2);
        WAITV(16);
        GROUP(xB, (g + 1) * 8);
        LOADG(xB, g + 3);
        WAITV(16);
    }
    GROUP(xA, 992);  LOADG(xA, 126); WAITV(16);
    GROUP(xB, 1000); LOADG(xB, 127); WAITV(16);
    GROUP(xA, 1008); WAITV(8);
    GROUP(xB, 1016);

    *hlast = h;
}

extern "C" void kernel_launch(void* const* d_in, const int* in_sizes, int n_in,
                              void* d_out, int out_size, void* d_ws, size_t ws_size,
                              hipStream_t stream) {
    const float* x    = (const float*)d_in[0];
    const float* w_ih = (const float*)d_in[1];
    const float* w_hh = (const float*)d_in[2];
    const float* b_ih = (const float*)d_in[3];
    const float* b_hh = (const float*)d_in[4];
    float* out = (float*)d_out;
    gru_kernel<<<BB / 8, 64, 0, stream>>>(x, w_ih, w_hh, b_ih, b_hh, out);
}

// Round 13
// 137.535 us; speedup vs baseline: 1.9377x; 1.1362x over previous
//
#include <hip/hip_runtime.h>

#define SS 1024
#define BB 4096
#define HH 8
#define XSTRIDE (BB * HH)   // floats per timestep slice

// DPP cross-lane (VALU pipe). quad_perm xor1/2/3; row_half_mirror (s^7);
// row_ror:8 (s^8 within each 16-lane row).
__device__ __forceinline__ int dpp_x1(int v) { return __builtin_amdgcn_mov_dpp(v, 0xB1, 0xF, 0xF, true); }
__device__ __forceinline__ int dpp_x2(int v) { return __builtin_amdgcn_mov_dpp(v, 0x4E, 0xF, 0xF, true); }
__device__ __forceinline__ int dpp_x3(int v) { return __builtin_amdgcn_mov_dpp(v, 0x1B, 0xF, 0xF, true); }
__device__ __forceinline__ int dpp_x7(int v) { return __builtin_amdgcn_mov_dpp(v, 0x141, 0xF, 0xF, true); }
__device__ __forceinline__ int dpp_r8(int v) { return __builtin_amdgcn_mov_dpp(v, 0x128, 0xF, 0xF, true); }

// Pinned distributed load: 4B/lane (element e0 of this lane's batch).
#define ALOADD(DST, PTR) asm volatile("global_load_dword %0, %1, off" : "=v"(DST) : "v"(PTR))

#define WAITV(N) do {                                                                  \
    asm volatile("s_waitcnt vmcnt(" #N ")" ::: "memory");                              \
    __builtin_amdgcn_sched_barrier(0);                                                 \
} while (0)

// Full X pre-activation for step V. Lane covers 4 columns {e0^0..e0^3} of its
// row; partner (s^8) covers the complementary 4; combine via row_ror:8.
// Commutative grouping (own + partner) => both replicas bit-identical.
#define XFULL(BUF, V) do {                                                             \
    const float va = BUF[V];                                                           \
    const int vai = __float_as_int(va);                                                \
    const float vb = __int_as_float(dpp_x1(vai));                                      \
    const float vc = __int_as_float(dpp_x2(vai));                                      \
    const float vd = __int_as_float(dpp_x3(vai));                                      \
    float sr0 = fmaf(va, wri[0], bias_rx); sr0 = fmaf(vb, wri[1], sr0);                \
    float sr1 = vc * wri[2];               sr1 = fmaf(vd, wri[3], sr1);                \
    float sz0 = fmaf(va, wzi[0], bias_zx); sz0 = fmaf(vb, wzi[1], sz0);                \
    float sz1 = vc * wzi[2];               sz1 = fmaf(vd, wzi[3], sz1);                \
    float sn0 = fmaf(va, wni[0], bias_nx); sn0 = fmaf(vb, wni[1], sn0);                \
    float sn1 = vc * wni[2];               sn1 = fmaf(vd, wni[3], sn1);                \
    const float srt = sr0 + sr1, szt = sz0 + sz1, snt = sn0 + sn1;                     \
    xr[V] = srt + __int_as_float(dpp_r8(__float_as_int(srt)));                         \
    xz[V] = szt + __int_as_float(dpp_r8(__float_as_int(szt)));                         \
    xn[V] = snt + __int_as_float(dpp_r8(__float_as_int(snt)));                         \
} while (0)

// One 8-step group: R-steps with X(u+2) woven (3 slices) into the
// transcendental stall windows.
#define GROUP(BUF, SBASE) do {                                                         \
    XFULL(BUF, 0);                                                                     \
    XFULL(BUF, 1);                                                                     \
    _Pragma("unroll")                                                                  \
    for (int u = 0; u < 8; ++u) {                                                      \
        /* h-dots: 12 FMA over this lane's 4 columns */                                \
        const int hvi = __float_as_int(hv);                                            \
        const float ha = hv;                                                           \
        const float hbv = __int_as_float(dpp_x1(hvi));                                 \
        const float hc = __int_as_float(dpp_x2(hvi));                                  \
        const float hd = __int_as_float(dpp_x3(hvi));                                  \
        float pr0 = ha * wrh[0];               pr0 = fmaf(hbv, wrh[1], pr0);           \
        float pr1 = hc * wrh[2];               pr1 = fmaf(hd, wrh[3], pr1);            \
        float pz0 = ha * wzh[0];               pz0 = fmaf(hbv, wzh[1], pz0);           \
        float pz1 = hc * wzh[2];               pz1 = fmaf(hd, wzh[3], pz1);            \
        float pn0 = fmaf(ha, wnh[0], bias_nh); pn0 = fmaf(hbv, wnh[1], pn0);           \
        float pn1 = hc * wnh[2];               pn1 = fmaf(hd, wnh[3], pn1);            \
        const float prt = pr0 + pr1, pzt = pz0 + pz1, pnt = pn0 + pn1;                 \
        const float srr = xr[u] + (prt + __int_as_float(dpp_r8(__float_as_int(prt)))); \
        const float szz = xz[u] + (pzt + __int_as_float(dpp_r8(__float_as_int(pzt)))); \
        const float snn = pnt + __int_as_float(dpp_r8(__float_as_int(pnt)));           \
        const bool W = (u + 2 < 8);                                                    \
        float wsr0, wsr1, wsz0, wsz1, wsn0, wsn1;                                      \
        float wvc, wvd;                                                                \
        if (W) {   /* X(u+2) slice 1: dpp reads + first half chains */                 \
            const float va2 = BUF[u + 2];                                              \
            const int va2i = __float_as_int(va2);                                      \
            const float vb2 = __int_as_float(dpp_x1(va2i));                            \
            wvc = __int_as_float(dpp_x2(va2i));                                        \
            wvd = __int_as_float(dpp_x3(va2i));                                        \
            wsr0 = fmaf(va2, wri[0], bias_rx); wsr0 = fmaf(vb2, wri[1], wsr0);         \
            wsz0 = fmaf(va2, wzi[0], bias_zx); wsz0 = fmaf(vb2, wzi[1], wsz0);         \
            wsn0 = fmaf(va2, wni[0], bias_nx); wsn0 = fmaf(vb2, wni[1], wsn0);         \
        }                                                                              \
        const float er = __builtin_amdgcn_exp2f(srr);                                  \
        const float ez = __builtin_amdgcn_exp2f(szz);                                  \
        if (W) {   /* X(u+2) slice 2: second half chains */                            \
            wsr1 = wvc * wri[2]; wsr1 = fmaf(wvd, wri[3], wsr1);                       \
            wsz1 = wvc * wzi[2]; wsz1 = fmaf(wvd, wzi[3], wsz1);                       \
            wsn1 = wvc * wni[2]; wsn1 = fmaf(wvd, wni[3], wsn1);                       \
        }                                                                              \
        const float r_ = __builtin_amdgcn_rcpf(1.0f + er);                             \
        const float z_ = __builtin_amdgcn_rcpf(1.0f + ez);                             \
        if (W) {   /* X(u+2) slice 3: combine + stage */                               \
            const float srt = wsr0 + wsr1, szt = wsz0 + wsz1, snt = wsn0 + wsn1;       \
            xr[u + 2] = srt + __int_as_float(dpp_r8(__float_as_int(srt)));             \
            xz[u + 2] = szt + __int_as_float(dpp_r8(__float_as_int(szt)));             \
            xn[u + 2] = snt + __int_as_float(dpp_r8(__float_as_int(snt)));             \
        }                                                                              \
        const float en = __builtin_amdgcn_exp2f(fmaf(r_, snn, xn[u]));                 \
        const float n_ = fmaf(-2.0f, __builtin_amdgcn_rcpf(1.0f + en), 1.0f);          \
        h = n_ + z_ * (h - n_);                                                        \
        /* rebuild skewed replica: upper half needs h from lane s^4 (x7 then x3) */    \
        const int hbits = __float_as_int(h);                                           \
        const int tA = dpp_x7(hbits);                                                  \
        const int tB = dpp_x3(tA);                                                     \
        hv = hiHalf ? __int_as_float(tB) : h;                                          \
        /* dup-store: both replicas hold bit-identical h for row j */                  \
        __builtin_nontemporal_store(h, &op[(size_t)((SBASE) + u) * XSTRIDE]);          \
    }                                                                                  \
} while (0)

// 8 pinned dword loads = one 8-step group (1 per step per lane).
#define LOADG(BUF, GRP) do {                                                           \
    const float* bp_ = xq + (size_t)(GRP) * 8 * XSTRIDE;                               \
    _Pragma("unroll")                                                                  \
    for (int u_ = 0; u_ < 8; ++u_) ALOADD(BUF[u_], bp_ + (size_t)u_ * XSTRIDE);        \
} while (0)

// 16 lanes per batch element (row j = s&7, column-half = s>>3), 4 batches per
// wave, 1024 waves = 1 wave per SIMD: all SIMDs active, per-wave issue ~halved.
__global__ __launch_bounds__(64, 1) void gru_kernel(
    const float* __restrict__ x,
    const float* __restrict__ w_ih,
    const float* __restrict__ w_hh,
    const float* __restrict__ b_ih,
    const float* __restrict__ b_hh,
    float* __restrict__ out)
{
    const int lane = threadIdx.x;
    const int s16 = lane & 15;
    const int j = s16 & 7;
    const int half = s16 >> 3;
    const bool hiHalf = (half != 0);
    const int e0 = j ^ (half << 2);        // element replica this lane holds

    const float SR = -1.4426950408889634f; // -log2(e): sigmoid scale
    const float SN = 2.8853900817779268f;  // 2*log2(e): tanh scale

    // Weights for row j over this lane's 4 columns e0^m (pre-scaled).
    float wri[4], wzi[4], wni[4], wrh[4], wzh[4], wnh[4];
    #pragma unroll
    for (int m = 0; m < 4; ++m) {
        const int c = e0 ^ m;
        wri[m] = SR * w_ih[j * 8 + c];
        wzi[m] = SR * w_ih[(8 + j) * 8 + c];
        wni[m] = SN * w_ih[(16 + j) * 8 + c];
        wrh[m] = SR * w_hh[j * 8 + c];
        wzh[m] = SR * w_hh[(8 + j) * 8 + c];
        wnh[m] = SN * w_hh[(16 + j) * 8 + c];
    }
    // Biases live only in the lower-half partials (combine adds them once).
    const float bias_rx = hiHalf ? 0.0f : SR * (b_ih[j] + b_hh[j]);
    const float bias_zx = hiHalf ? 0.0f : SR * (b_ih[8 + j] + b_hh[8 + j]);
    const float bias_nx = hiHalf ? 0.0f : SN * b_ih[16 + j];
    const float bias_nh = hiHalf ? 0.0f : SN * b_hh[16 + j];

    // Addresses: batch bg = blockIdx*4 + (lane>>4). Loads fetch element e0
    // (skewed replica); stores write row j (dup across halves, same value).
    const float* xq = x + (blockIdx.x << 5) + ((lane >> 4) << 3) + e0;
    float* op = out + (blockIdx.x << 5) + ((lane >> 4) << 3) + j;
    float* hlast = out + (size_t)SS * BB * HH + (blockIdx.x << 5) + ((lane >> 4) << 3) + j;

    float xA[8], xB[8];   // distributed x: 1 dword/lane/step

    // prologue: groups 0 -> A, 1 -> B; retire A's 8 (B's 8 stay in flight)
    LOADG(xA, 0);
    LOADG(xB, 1);
    WAITV(8);

    float h = 0.0f;
    float hv = 0.0f;      // skewed replica of h (h[e0])
    float xr[8], xz[8], xn[8];

    // Steady state at each WAITV(16): newest 16 = this group's 8 stores +
    // just-issued 8 loads; the other buffer's (older) loads are retired.
    for (int g = 0; g < 124; g += 2) {
        GROUP(xA, g * 8);
        LOADG(xA, g + 2);
        WAITV(16);
        GROUP(xB, (g + 1) * 8);
        LOADG(xB, g + 3);
        WAITV(16);
    }
    GROUP(xA, 992);  LOADG(xA, 126); WAITV(16);
    GROUP(xB, 1000); LOADG(xB, 127); WAITV(16);
    GROUP(xA, 1008); WAITV(8);
    GROUP(xB, 1016);

    *hlast = h;
}

extern "C" void kernel_launch(void* const* d_in, const int* in_sizes, int n_in,
                              void* d_out, int out_size, void* d_ws, size_t ws_size,
                              hipStream_t stream) {
    const float* x    = (const float*)d_in[0];
    const float* w_ih = (const float*)d_in[1];
    const float* w_hh = (const float*)d_in[2];
    const float* b_ih = (const float*)d_in[3];
    const float* b_hh = (const float*)d_in[4];
    float* out = (float*)d_out;
    gru_kernel<<<BB / 4, 64, 0, stream>>>(x, w_ih, w_hh, b_ih, b_hh, out);
}